// Round 5
// baseline (354.371 us; speedup 1.0000x reference)
//
#include <hip/hip_runtime.h>
#include <math.h>

// s = sum_i R[i] * ||Z[i,:]||^2 ;  out = 1 - exp(-exp(s))
// Z: (500000,128) fp32 = 256 MB, R: 2 MB. The harness's d_in restore runs
// right before this kernel each iteration and leaves Z hot in the 256 MB
// Infinity Cache -- so plain (cached) loads, NOT nontemporal, should serve
// most of Z from LLC. Grid = 4096 blocks = exactly 16 blocks/CU (no tail
// straggler CUs); 15 full float4/thread + 1 guarded.

#define NROWS   500000
#define DCOLS   128
#define N4      (NROWS * DCOLS / 4)    // 16,000,000 float4
#define BLOCK   256
#define GRID    4096
#define NTH     (GRID * BLOCK)         // 1,048,576 threads
#define FULL    15                     // 15*NTH = 15,728,640 < N4; u=15 guarded

typedef float floatx4 __attribute__((ext_vector_type(4)));

__device__ __forceinline__ float dot4w(float w, floatx4 v) {
    return w * (v.x * v.x + v.y * v.y + v.z * v.z + v.w * v.w);
}

__global__ void __launch_bounds__(BLOCK)
bp_reduce(const float* __restrict__ Z, const float* __restrict__ R,
          float* __restrict__ partial) {
    const floatx4* __restrict__ Z4 = (const floatx4*)Z;
    const int tid = blockIdx.x * BLOCK + threadIdx.x;

    float acc = 0.0f;

    // batch 1: u = 0..7  (8 independent dwordx4 in flight)
    {
        floatx4 v[8]; float w[8];
        #pragma unroll
        for (int u = 0; u < 8; ++u) {
            const int idx = tid + u * NTH;
            v[u] = Z4[idx];
            w[u] = R[idx >> 5];   // row = (4*idx)/128; 32 lanes share -> L1 broadcast
        }
        #pragma unroll
        for (int u = 0; u < 8; ++u) acc += dot4w(w[u], v[u]);
    }
    // batch 2: u = 8..14
    {
        floatx4 v[7]; float w[7];
        #pragma unroll
        for (int u = 0; u < 7; ++u) {
            const int idx = tid + (u + 8) * NTH;
            v[u] = Z4[idx];
            w[u] = R[idx >> 5];
        }
        #pragma unroll
        for (int u = 0; u < 7; ++u) acc += dot4w(w[u], v[u]);
    }
    // guarded tail: u = 15
    {
        const int idx = tid + FULL * NTH;
        if (idx < N4) {
            floatx4 v = Z4[idx];
            acc += dot4w(R[idx >> 5], v);
        }
    }

    // wave(64) shuffle reduction
    #pragma unroll
    for (int off = 32; off > 0; off >>= 1)
        acc += __shfl_down(acc, off, 64);

    __shared__ float smem[BLOCK / 64];
    const int wave = threadIdx.x >> 6;
    const int lane = threadIdx.x & 63;
    if (lane == 0) smem[wave] = acc;
    __syncthreads();

    if (threadIdx.x == 0)
        partial[blockIdx.x] = smem[0] + smem[1] + smem[2] + smem[3];
}

__global__ void __launch_bounds__(BLOCK)
bp_finalize(const float* __restrict__ partial, float* __restrict__ out) {
    float acc = 0.0f;
    #pragma unroll
    for (int i = threadIdx.x; i < GRID; i += BLOCK)
        acc += partial[i];

    #pragma unroll
    for (int off = 32; off > 0; off >>= 1)
        acc += __shfl_down(acc, off, 64);

    __shared__ float smem[BLOCK / 64];
    const int wave = threadIdx.x >> 6;
    const int lane = threadIdx.x & 63;
    if (lane == 0) smem[wave] = acc;
    __syncthreads();

    if (threadIdx.x == 0) {
        float s = smem[0] + smem[1] + smem[2] + smem[3];
        float lam = expf(s);
        out[0] = 1.0f - expf(-lam);
    }
}

extern "C" void kernel_launch(void* const* d_in, const int* in_sizes, int n_in,
                              void* d_out, int out_size, void* d_ws, size_t ws_size,
                              hipStream_t stream) {
    const float* Z = (const float*)d_in[0];
    const float* R = (const float*)d_in[1];
    float* out = (float*)d_out;
    float* partial = (float*)d_ws;   // 4096 floats = 16 KB << ws_size

    bp_reduce<<<GRID, BLOCK, 0, stream>>>(Z, R, partial);
    bp_finalize<<<1, BLOCK, 0, stream>>>(partial, out);
}

// Round 6
// 325.787 us; speedup vs baseline: 1.0877x; 1.0877x over previous
//
#include <hip/hip_runtime.h>
#include <math.h>

// s = sum_i R[i] * ||Z[i,:]||^2 ;  out = 1 - exp(-exp(s))
// Z: (500000,128) fp32 = 256 MB (streamed once), R: 2 MB.
//
// Measured across rounds: NONTEMPORAL Z loads are ~35 us faster than cached.
// Model: the harness's 1 GB ws-poison fill leaves the 256 MB LLC full of
// dirty lines; cached Z reads allocate -> force dirty writebacks onto the
// critical path (~2x traffic). NT reads don't allocate -> pure 256 MB stream.
// Occupancy is not the limiter (12 vs 32 waves/CU measured identical).
// Grid 4096 = exactly 16 blocks/CU (2500 gave 9.77/CU -> straggler tail).

#define NROWS   500000
#define DCOLS   128
#define N4      (NROWS * DCOLS / 4)    // 16,000,000 float4
#define BLOCK   256
#define GRID    4096
#define NTH     (GRID * BLOCK)         // 1,048,576 threads
#define FULL    15                     // floor(16M / 1.048576M); u=15 guarded

typedef float floatx4 __attribute__((ext_vector_type(4)));

__device__ __forceinline__ float dot4w(float w, floatx4 v) {
    return w * (v.x * v.x + v.y * v.y + v.z * v.z + v.w * v.w);
}

__global__ void __launch_bounds__(BLOCK)
bp_reduce(const float* __restrict__ Z, const float* __restrict__ R,
          float* __restrict__ partial) {
    const floatx4* __restrict__ Z4 = (const floatx4*)Z;
    const int tid = blockIdx.x * BLOCK + threadIdx.x;

    float acc = 0.0f;

    // batch 1: u = 0..7 (8 independent NT dwordx4 in flight; VGPR ~ 40)
    {
        floatx4 v[8]; float w[8];
        #pragma unroll
        for (int u = 0; u < 8; ++u) {
            const int idx = tid + u * NTH;
            v[u] = __builtin_nontemporal_load(&Z4[idx]);
            w[u] = R[idx >> 5];   // row = (4*idx)/128; 32 lanes share -> L1 broadcast
        }
        #pragma unroll
        for (int u = 0; u < 8; ++u) acc += dot4w(w[u], v[u]);
    }
    // batch 2: u = 8..14
    {
        floatx4 v[7]; float w[7];
        #pragma unroll
        for (int u = 0; u < 7; ++u) {
            const int idx = tid + (u + 8) * NTH;
            v[u] = __builtin_nontemporal_load(&Z4[idx]);
            w[u] = R[idx >> 5];
        }
        #pragma unroll
        for (int u = 0; u < 7; ++u) acc += dot4w(w[u], v[u]);
    }
    // guarded tail: u = 15 (first 271,360 threads only)
    {
        const int idx = tid + FULL * NTH;
        if (idx < N4) {
            floatx4 v = __builtin_nontemporal_load(&Z4[idx]);
            acc += dot4w(R[idx >> 5], v);
        }
    }

    // wave(64) shuffle reduction
    #pragma unroll
    for (int off = 32; off > 0; off >>= 1)
        acc += __shfl_down(acc, off, 64);

    __shared__ float smem[BLOCK / 64];
    const int wave = threadIdx.x >> 6;
    const int lane = threadIdx.x & 63;
    if (lane == 0) smem[wave] = acc;
    __syncthreads();

    if (threadIdx.x == 0)
        partial[blockIdx.x] = smem[0] + smem[1] + smem[2] + smem[3];
}

__global__ void __launch_bounds__(BLOCK)
bp_finalize(const float* __restrict__ partial, float* __restrict__ out) {
    float acc = 0.0f;
    #pragma unroll
    for (int i = threadIdx.x; i < GRID; i += BLOCK)
        acc += partial[i];

    #pragma unroll
    for (int off = 32; off > 0; off >>= 1)
        acc += __shfl_down(acc, off, 64);

    __shared__ float smem[BLOCK / 64];
    const int wave = threadIdx.x >> 6;
    const int lane = threadIdx.x & 63;
    if (lane == 0) smem[wave] = acc;
    __syncthreads();

    if (threadIdx.x == 0) {
        float s = smem[0] + smem[1] + smem[2] + smem[3];
        float lam = expf(s);
        out[0] = 1.0f - expf(-lam);
    }
}

extern "C" void kernel_launch(void* const* d_in, const int* in_sizes, int n_in,
                              void* d_out, int out_size, void* d_ws, size_t ws_size,
                              hipStream_t stream) {
    const float* Z = (const float*)d_in[0];
    const float* R = (const float*)d_in[1];
    float* out = (float*)d_out;
    float* partial = (float*)d_ws;   // 4096 floats = 16 KB << ws_size

    bp_reduce<<<GRID, BLOCK, 0, stream>>>(Z, R, partial);
    bp_finalize<<<1, BLOCK, 0, stream>>>(partial, out);
}